// Round 8
// baseline (105.764 us; speedup 1.0000x reference)
//
#include <hip/hip_runtime.h>
#include <math.h>

#define CC 30
#define NBATCH 4096
#define NIJ 49
#define NPAIR 1225            // 49 ij * 25 tail channels (c = 5..29)
#define PSTR 7352             // per-wg partial stride in floats (6*NPAIR=7350, padded to /4)
#define F4TOT (PSTR / 4)      // 1838 float4 columns
#define THREADS 512
#define SLABF4 1470           // float4 count of a 4-batch slab
#define TOKEN 0x7E57C0DE

// ws layout (no initialization required; barrier flags are token-checked and
// reset by yolo_final for the next call):
//   offset 0     : flags[256] int      (reset to 0 by yolo_final)
//   offset 4096  : sc[nwg] float       (written by yolo_fused)
//   offset 8192  : tbl[PSTR] float     (written by yolo_fused reduce phase)
//   offset 49152 : parts[nwg][PSTR]    (written by yolo_fused)

__global__ __launch_bounds__(THREADS)
void yolo_fused(const float* __restrict__ y, const float* __restrict__ yh,
                int* __restrict__ flags, float* __restrict__ sc,
                float* __restrict__ tbl, float* __restrict__ parts, int nwg)
{
    __shared__ __align__(16) float tY[4 * 1470];   // 23.5 KB
    __shared__ __align__(16) float tH[4 * 1470];   // 23.5 KB
    __shared__ float scr[4][8];
    __shared__ float scrw[4];

    const int tid = threadIdx.x;
    const int wg  = blockIdx.x;
    const int bpw = NBATCH / nwg;
    const int nslab = bpw >> 2;

    const int i0 = tid, i1 = tid + 512;
    const int i2r = tid + 1024;
    const int i2  = (i2r < SLABF4) ? i2r : (SLABF4 - 1);
    const bool w2 = (i2r < SLABF4);

    int  ijv[3], cv[3], pr[3];
    bool val[3];
    #pragma unroll
    for (int i = 0; i < 3; i++) {
        int p = tid + i * THREADS;
        val[i] = (p < NPAIR);
        pr[i]  = p;
        int pp = val[i] ? p : 0;
        ijv[i] = pp / 25;
        cv[i]  = 5 + pp % 25;
    }

    float D0[3] = {0,0,0}, B0[3] = {0,0,0}, C0[3] = {0,0,0};
    float D1[3] = {0,0,0}, B1[3] = {0,0,0}, C1[3] = {0,0,0};
    float obj = 0.f, noobj = 0.f, coord = 0.f, tt = 0.f;

    const float4* Yg = (const float4*)y;
    const float4* Hg = (const float4*)yh;
    float4* tY4 = (float4*)tY;
    float4* tH4 = (float4*)tH;

    // prologue: stage slab 0
    {
        const size_t f4 = (size_t)((wg * bpw) >> 2) * SLABF4;
        float4 a0 = Yg[f4+i0], a1 = Yg[f4+i1], a2 = Yg[f4+i2];
        float4 b0 = Hg[f4+i0], b1 = Hg[f4+i1], b2 = Hg[f4+i2];
        tY4[i0] = a0; tY4[i1] = a1; if (w2) tY4[i2] = a2;
        tH4[i0] = b0; tH4[i1] = b1; if (w2) tH4[i2] = b2;
    }
    __syncthreads();

    float4 ry0, ry1, ry2, rh0, rh1, rh2;

    for (int s = 0; s < nslab; s++) {
        if (s + 1 < nslab) {     // prefetch next slab into registers (T14)
            const size_t nf4 = (size_t)((wg * bpw + (s+1)*4) >> 2) * SLABF4;
            ry0 = Yg[nf4+i0]; ry1 = Yg[nf4+i1]; ry2 = Yg[nf4+i2];
            rh0 = Hg[nf4+i0]; rh1 = Hg[nf4+i1]; rh2 = Hg[nf4+i2];
        }

        if (tid < 4 * NIJ) {
            const int base = tid * CC;
            float y0 = tY[base],     h0 = tH[base];
            float y5 = tY[base + 5], h5 = tH[base + 5];
            float d0 = y0 - h0; d0 *= d0;
            float d5 = y5 - h5; d5 *= d5;
            const bool m0 = (y0 == 1.0f), m1 = (y5 == 1.0f);
            obj   += (m0 ? d0 : 0.f) + (m1 ? d5 : 0.f);
            noobj += (m0 ? 0.f : d0) + (m1 ? 0.f : d5);
            if (m0) {
                float a  = tY[base + 1] - tH[base + 1];
                float b2 = tY[base + 2] - tH[base + 2];
                float c1 = sqrtf(tY[base + 3]) - sqrtf(tH[base + 3]);
                float c2 = sqrtf(tY[base + 4]) - sqrtf(tH[base + 4]);
                coord += a * a + b2 * b2 + c1 * c1 + c2 * c2;
            }
            if (m1) {
                float a  = tY[base + 6] - tH[base + 6];
                float b2 = tY[base + 7] - tH[base + 7];
                float c1 = sqrtf(tY[base + 8]) - sqrtf(tH[base + 8]);
                float c2 = sqrtf(tY[base + 9]) - sqrtf(tH[base + 9]);
                coord += a * a + b2 * b2 + c1 * c1 + c2 * c2;
            }
        }

        #pragma unroll
        for (int b = 0; b < 4; b++) {
            #pragma unroll
            for (int i = 0; i < 3; i++) {
                if (!val[i]) continue;
                const int cb = b * 1470 + ijv[i] * CC;
                const float w0 = (tY[cb] == 1.0f) ? 1.f : 0.f;
                const float w1 = (cv[i] >= 10 && tY[cb + 5] == 1.0f) ? 1.f : 0.f;
                const float t  = tY[cb + cv[i]];
                const float th = tH[cb + cv[i]];
                const float e  = __expf(th);
                const float te = t * e, ee = e * e, t2 = t * t;
                D0[i] = fmaf(e,  w0, D0[i]);
                B0[i] = fmaf(te, w0, B0[i]);
                C0[i] = fmaf(ee, w0, C0[i]);
                D1[i] = fmaf(e,  w1, D1[i]);
                B1[i] = fmaf(te, w1, B1[i]);
                C1[i] = fmaf(ee, w1, C1[i]);
                tt = fmaf(t2, w0 + w1, tt);
            }
        }
        __syncthreads();
        if (s + 1 < nslab) {
            tY4[i0] = ry0; tY4[i1] = ry1; if (w2) tY4[i2] = ry2;
            tH4[i0] = rh0; tH4[i1] = rh1; if (w2) tH4[i2] = rh2;
        }
        __syncthreads();
    }

    // ---- per-wg partials: contiguous block, coalesced stores ----
    float* pp = parts + (size_t)wg * PSTR;
    #pragma unroll
    for (int i = 0; i < 3; i++) {
        if (!val[i]) continue;
        const int p = pr[i];
        pp[p]            = D0[i];
        pp[NPAIR + p]    = B0[i];
        pp[2*NPAIR + p]  = C0[i];
        pp[3*NPAIR + p]  = D1[i];
        pp[4*NPAIR + p]  = B1[i];
        pp[5*NPAIR + p]  = C1[i];
    }

    // ---- weighted scalar sum -> sc[wg] ----
    const int lane = tid & 63, wv = tid >> 6;
    #pragma unroll
    for (int off = 32; off > 0; off >>= 1) {
        obj   += __shfl_down(obj,   off);
        noobj += __shfl_down(noobj, off);
        coord += __shfl_down(coord, off);
        tt    += __shfl_down(tt,    off);
    }
    if (lane == 0) { scr[0][wv] = obj; scr[1][wv] = noobj; scr[2][wv] = coord; scr[3][wv] = tt; }
    __syncthreads();
    if (tid < 4) {
        float sacc = 0.f;
        #pragma unroll
        for (int w = 0; w < THREADS / 64; w++) sacc += scr[tid][w];
        const float wts[4] = {1.f, 0.5f, 5.f, 1.f};
        scrw[tid] = sacc * wts[tid];
    }
    __syncthreads();
    if (tid == 0) sc[wg] = scrw[0] + scrw[1] + scrw[2] + scrw[3];

    // ---- device-scope grid barrier (all nwg blocks resident by construction) ----
    __syncthreads();
    __threadfence();
    if (tid == 0)
        __hip_atomic_store(&flags[wg], TOKEN, __ATOMIC_RELEASE, __HIP_MEMORY_SCOPE_AGENT);
    for (int f = tid; f < nwg; f += THREADS) {
        while (__hip_atomic_load(&flags[f], __ATOMIC_ACQUIRE, __HIP_MEMORY_SCOPE_AGENT) != TOKEN)
            __builtin_amdgcn_s_sleep(1);
    }
    __threadfence();
    __syncthreads();

    // ---- distributed reduce: parts -> tbl (coalesced float4, fixed order) ----
    const int F4PB = (F4TOT + nwg - 1) / nwg;          // 8 for nwg=256
    float4* sacc4 = (float4*)tY;                        // reuse LDS (8 KB)
    const float4* parts4 = (const float4*)parts;        // row stride F4TOT
    float4* tbl4 = (float4*)tbl;

    for (int pass = 0; pass < (F4PB + 7) / 8; pass++) {
        const int k = pass * 8 + (tid & 7);
        const int f = wg * F4PB + k;
        float4 sv = make_float4(0.f, 0.f, 0.f, 0.f);
        if (k < F4PB && f < F4TOT) {
            const float4* q = parts4 + (size_t)(tid >> 3) * F4TOT + f;
            for (int r = tid >> 3; r < nwg; r += 64) {
                float4 a = *q;
                sv.x += a.x; sv.y += a.y; sv.z += a.z; sv.w += a.w;
                q += (size_t)64 * F4TOT;
            }
        }
        sacc4[tid] = sv;
        __syncthreads();
        #pragma unroll
        for (int off = 256; off >= 8; off >>= 1) {
            if (tid < off) {
                float4 a = sacc4[tid], b = sacc4[tid + off];
                a.x += b.x; a.y += b.y; a.z += b.z; a.w += b.w;
                sacc4[tid] = a;
            }
            __syncthreads();
        }
        if (tid < 8) {
            const int kk = pass * 8 + tid;
            const int ff = wg * F4PB + kk;
            if (kk < F4PB && ff < F4TOT) tbl4[ff] = sacc4[tid];
        }
        __syncthreads();
    }
}

__global__ __launch_bounds__(1024)
void yolo_final(const float* __restrict__ tbl, const float* __restrict__ sc,
                int* __restrict__ flags, float* __restrict__ out, int nwg)
{
    float v = 0.f;

    for (int s = threadIdx.x; s < NPAIR; s += 1024) {
        const int cidx = s % 25;
        float D0 = tbl[s], B0 = tbl[NPAIR + s], C0 = tbl[2*NPAIR + s];
        if (D0 > 0.f) v += C0 / (D0 * D0) - 2.f * B0 / D0;
        if (cidx >= 5) {
            float D1 = tbl[3*NPAIR + s], B1 = tbl[4*NPAIR + s], C1 = tbl[5*NPAIR + s];
            if (D1 > 0.f) v += C1 / (D1 * D1) - 2.f * B1 / D1;
        }
    }
    for (int w = threadIdx.x; w < nwg; w += 1024) v += sc[w];

    __shared__ float sred[16];
    #pragma unroll
    for (int off = 32; off > 0; off >>= 1) v += __shfl_down(v, off);
    const int lane = threadIdx.x & 63, wv = threadIdx.x >> 6;
    if (lane == 0) sred[wv] = v;
    __syncthreads();
    if (threadIdx.x == 0) {
        float tot = 0.f;
        #pragma unroll
        for (int w = 0; w < 16; w++) tot += sred[w];
        out[0] = tot / (float)NBATCH;
    }
    // reset barrier flags for the next call (visible at next kernel launch)
    if (threadIdx.x < 256) flags[threadIdx.x] = 0;
}

extern "C" void kernel_launch(void* const* d_in, const int* in_sizes, int n_in,
                              void* d_out, int out_size, void* d_ws, size_t ws_size,
                              hipStream_t stream)
{
    const float* y  = (const float*)d_in[0];
    const float* yh = (const float*)d_in[1];
    float* out   = (float*)d_out;
    int*   flags = (int*)d_ws;
    float* sc    = (float*)((char*)d_ws + 4096);
    float* tbl   = (float*)((char*)d_ws + 8192);
    float* parts = (float*)((char*)d_ws + 49152);

    const size_t per_wg = (size_t)PSTR * sizeof(float);   // 29.4 KB
    int nwg;
    if      (ws_size >= 49152 + 256 * per_wg) nwg = 256;
    else if (ws_size >= 49152 + 128 * per_wg) nwg = 128;
    else                                      nwg = 64;

    yolo_fused<<<nwg, THREADS, 0, stream>>>(y, yh, flags, sc, tbl, parts, nwg);
    yolo_final<<<1, 1024, 0, stream>>>(tbl, sc, flags, out, nwg);
}

// Round 9
// 31.509 us; speedup vs baseline: 3.3567x; 3.3567x over previous
//
#include <hip/hip_runtime.h>
#include <math.h>

#define CC 30
#define NBATCH 4096
#define NIJ 49
#define NPAIR 1225            // 49 ij * 25 tail channels (c = 5..29)
#define PSTR 7352             // per-wg partial stride in floats (6*NPAIR=7350, padded to /4)
#define F4TOT (PSTR / 4)
#define THREADS 512
#define SLABF4 1470           // float4 count of a 4-batch slab of ONE tensor

// ws layout (NO initialization required — every read location is written first):
//   offset 0      : scal[nwg][4]        (written by yolo_main)
//   offset 8192   : parts2[8][PSTR]     (written by yolo_reduce)
//   offset 243456 : parts[nwg][PSTR]    (written by yolo_main)

__global__ __launch_bounds__(THREADS)
void yolo_main(const float* __restrict__ y, const float* __restrict__ yh,
               float* __restrict__ scal, float* __restrict__ parts, int nwg)
{
    __shared__ __align__(16) float tY[4 * 1470];   // y only: 23.5 KB
    __shared__ float scr[4][8];

    const int tid = threadIdx.x;
    const int wg  = blockIdx.x;
    const int bpw = NBATCH / nwg;        // 8 for nwg=512
    const int nslab = bpw >> 2;

    const int i0 = tid, i1 = tid + 512;
    const int i2r = tid + 1024;
    const int i2  = (i2r < SLABF4) ? i2r : (SLABF4 - 1);
    const bool w2 = (i2r < SLABF4);

    int  ijv[3], cv[3], pr[3];
    bool val[3];
    #pragma unroll
    for (int i = 0; i < 3; i++) {
        int p = tid + i * THREADS;
        val[i] = (p < NPAIR);
        pr[i]  = p;
        int pp = val[i] ? p : 0;
        ijv[i] = pp / 25;
        cv[i]  = 5 + pp % 25;
    }

    float D0[3] = {0,0,0}, B0[3] = {0,0,0}, C0[3] = {0,0,0};
    float D1[3] = {0,0,0}, B1[3] = {0,0,0}, C1[3] = {0,0,0};
    float obj = 0.f, noobj = 0.f, coord = 0.f, tt = 0.f;

    const float4* Yg = (const float4*)y;
    float4* tY4 = (float4*)tY;

    // prologue: stage slab 0 (y only)
    {
        const size_t f4 = (size_t)((wg * bpw) >> 2) * SLABF4;
        float4 a0 = Yg[f4+i0], a1 = Yg[f4+i1], a2 = Yg[f4+i2];
        tY4[i0] = a0; tY4[i1] = a1; if (w2) tY4[i2] = a2;
    }
    __syncthreads();

    float4 ry0, ry1, ry2;

    for (int s = 0; s < nslab; s++) {
        const size_t gslab = (size_t)(wg * bpw + s * 4) * 1470;  // slab base (floats) in yh

        if (s + 1 < nslab) {     // prefetch next y-slab into registers
            const size_t nf4 = (size_t)((wg * bpw + (s+1)*4) >> 2) * SLABF4;
            ry0 = Yg[nf4+i0]; ry1 = Yg[nf4+i1]; ry2 = Yg[nf4+i2];
        }

        // ---- pointwise: 196 cells; y from LDS, yh straight from global ----
        if (tid < 4 * NIJ) {
            const int base = tid * CC;
            const float* hq = yh + gslab + base;
            float y0 = tY[base],     h0 = hq[0];
            float y5 = tY[base + 5], h5 = hq[5];
            float d0 = y0 - h0; d0 *= d0;
            float d5 = y5 - h5; d5 *= d5;
            const bool m0 = (y0 == 1.0f), m1 = (y5 == 1.0f);
            obj   += (m0 ? d0 : 0.f) + (m1 ? d5 : 0.f);
            noobj += (m0 ? 0.f : d0) + (m1 ? 0.f : d5);
            if (m0) {
                float a  = tY[base + 1] - hq[1];
                float b2 = tY[base + 2] - hq[2];
                float c1 = sqrtf(tY[base + 3]) - sqrtf(hq[3]);
                float c2 = sqrtf(tY[base + 4]) - sqrtf(hq[4]);
                coord += a * a + b2 * b2 + c1 * c1 + c2 * c2;
            }
            if (m1) {
                float a  = tY[base + 6] - hq[6];
                float b2 = tY[base + 7] - hq[7];
                float c1 = sqrtf(tY[base + 8]) - sqrtf(hq[8]);
                float c2 = sqrtf(tY[base + 9]) - sqrtf(hq[9]);
                coord += a * a + b2 * b2 + c1 * c1 + c2 * c2;
            }
        }

        // ---- slot phase: y (t, masks) from LDS; yh (exp input) from global ----
        #pragma unroll
        for (int b = 0; b < 4; b++) {
            #pragma unroll
            for (int i = 0; i < 3; i++) {
                if (!val[i]) continue;
                const int cb = b * 1470 + ijv[i] * CC;
                const float w0 = (tY[cb] == 1.0f) ? 1.f : 0.f;
                const float w1 = (cv[i] >= 10 && tY[cb + 5] == 1.0f) ? 1.f : 0.f;
                const float t  = tY[cb + cv[i]];
                const float th = yh[gslab + cb + cv[i]];
                const float e  = __expf(th);
                const float te = t * e, ee = e * e, t2 = t * t;
                D0[i] = fmaf(e,  w0, D0[i]);
                B0[i] = fmaf(te, w0, B0[i]);
                C0[i] = fmaf(ee, w0, C0[i]);
                D1[i] = fmaf(e,  w1, D1[i]);
                B1[i] = fmaf(te, w1, B1[i]);
                C1[i] = fmaf(ee, w1, C1[i]);
                tt = fmaf(t2, w0 + w1, tt);
            }
        }
        __syncthreads();
        if (s + 1 < nslab) {
            tY4[i0] = ry0; tY4[i1] = ry1; if (w2) tY4[i2] = ry2;
        }
        __syncthreads();
    }

    // ---- per-wg partials: contiguous block, coalesced stores ----
    float* pp = parts + (size_t)wg * PSTR;
    #pragma unroll
    for (int i = 0; i < 3; i++) {
        if (!val[i]) continue;
        const int p = pr[i];
        pp[p]            = D0[i];
        pp[NPAIR + p]    = B0[i];
        pp[2*NPAIR + p]  = C0[i];
        pp[3*NPAIR + p]  = D1[i];   // zero when cv<10 (w1 never set)
        pp[4*NPAIR + p]  = B1[i];
        pp[5*NPAIR + p]  = C1[i];
    }

    // ---- scalar sums: shuffle -> LDS -> 4 floats per wg ----
    const int lane = tid & 63, wv = tid >> 6;
    #pragma unroll
    for (int off = 32; off > 0; off >>= 1) {
        obj   += __shfl_down(obj,   off);
        noobj += __shfl_down(noobj, off);
        coord += __shfl_down(coord, off);
        tt    += __shfl_down(tt,    off);
    }
    if (lane == 0) { scr[0][wv] = obj; scr[1][wv] = noobj; scr[2][wv] = coord; scr[3][wv] = tt; }
    __syncthreads();
    if (tid < 4) {
        float sacc = 0.f;
        #pragma unroll
        for (int w = 0; w < THREADS / 64; w++) sacc += scr[tid][w];
        scal[wg * 4 + tid] = sacc;
    }
}

// grid (29, 8) x 512: block (bx, cy) sums 64 float4-columns over 1/8 of the wgs
// (8-way sub-split inside the block), float4 loads, LDS fold, plain store.
__global__ __launch_bounds__(512)
void yolo_reduce(const float* __restrict__ parts, float* __restrict__ parts2, int nwg)
{
    const int lane = threadIdx.x & 63;          // float4 column lane
    const int sub  = threadIdx.x >> 6;          // 0..7
    const int f4i  = blockIdx.x * 64 + lane;
    const int cy   = blockIdx.y;                // 0..7
    const int wpc  = nwg >> 3;                  // wgs per chunk
    const int wps  = wpc >> 3;                  // wgs per sub-group

    float4 s = make_float4(0.f, 0.f, 0.f, 0.f);
    if (f4i < F4TOT) {
        const float* q = parts + (size_t)(cy * wpc + sub * wps) * PSTR + f4i * 4;
        for (int w = 0; w < wps; ++w) {
            float4 a = *(const float4*)q;
            s.x += a.x; s.y += a.y; s.z += a.z; s.w += a.w;
            q += PSTR;
        }
    }
    __shared__ float4 sred[8][64];
    sred[sub][lane] = s;
    __syncthreads();
    if (threadIdx.x < 64 && f4i < F4TOT) {
        float4 t = sred[0][lane];
        #pragma unroll
        for (int c = 1; c < 8; c++) {
            float4 a = sred[c][lane];
            t.x += a.x; t.y += a.y; t.z += a.z; t.w += a.w;
        }
        *(float4*)(parts2 + (size_t)cy * PSTR + f4i * 4) = t;
    }
}

__global__ __launch_bounds__(1024)
void yolo_final(const float* __restrict__ parts2, const float* __restrict__ scal,
                float* __restrict__ out, int nwg)
{
    float v = 0.f;

    for (int s = threadIdx.x; s < NPAIR; s += 1024) {
        const int cidx = s % 25;
        float D0 = 0, B0 = 0, C0 = 0, D1 = 0, B1 = 0, C1 = 0;
        #pragma unroll
        for (int c = 0; c < 8; c++) {
            const float* t = parts2 + (size_t)c * PSTR;
            D0 += t[s];           B0 += t[NPAIR + s];   C0 += t[2*NPAIR + s];
            D1 += t[3*NPAIR + s]; B1 += t[4*NPAIR + s]; C1 += t[5*NPAIR + s];
        }
        if (D0 > 0.f) v += C0 / (D0 * D0) - 2.f * B0 / D0;
        if (cidx >= 5 && D1 > 0.f) v += C1 / (D1 * D1) - 2.f * B1 / D1;
    }

    const float4* s4 = (const float4*)scal;
    for (int w = threadIdx.x; w < nwg; w += 1024) {
        float4 a = s4[w];
        v += a.x + 0.5f * a.y + 5.0f * a.z + a.w;
    }

    __shared__ float sred[16];
    #pragma unroll
    for (int off = 32; off > 0; off >>= 1) v += __shfl_down(v, off);
    const int lane = threadIdx.x & 63, wv = threadIdx.x >> 6;
    if (lane == 0) sred[wv] = v;
    __syncthreads();
    if (threadIdx.x == 0) {
        float tot = 0.f;
        #pragma unroll
        for (int w = 0; w < 16; w++) tot += sred[w];
        out[0] = tot / (float)NBATCH;
    }
}

extern "C" void kernel_launch(void* const* d_in, const int* in_sizes, int n_in,
                              void* d_out, int out_size, void* d_ws, size_t ws_size,
                              hipStream_t stream)
{
    const float* y  = (const float*)d_in[0];
    const float* yh = (const float*)d_in[1];
    float* out    = (float*)d_out;
    float* scal   = (float*)d_ws;
    float* parts2 = (float*)((char*)d_ws + 8192);
    float* parts  = (float*)((char*)d_ws + 243456);

    const size_t per_wg = (size_t)PSTR * sizeof(float);   // 29.4 KB
    int nwg;
    if      (ws_size >= 243456 + 512 * per_wg) nwg = 512;
    else if (ws_size >= 243456 + 256 * per_wg) nwg = 256;
    else                                       nwg = 128;

    yolo_main<<<nwg, THREADS, 0, stream>>>(y, yh, scal, parts, nwg);
    dim3 g2((F4TOT + 63) / 64, 8);
    yolo_reduce<<<g2, 512, 0, stream>>>(parts, parts2, nwg);
    yolo_final<<<1, 1024, 0, stream>>>(parts2, scal, out, nwg);
}